// Round 4
// baseline (87.492 us; speedup 1.0000x reference)
//
#include <hip/hip_runtime.h>

#define H 16
#define DK 64
#define SD 1024
#define DD 1024
#define BB 2
#define MROWS (BB * SD)   // 2048
#define KDIM 1024

typedef __attribute__((ext_vector_type(8))) short short8;
typedef __attribute__((ext_vector_type(4))) float floatx4;
typedef unsigned short u16;
typedef __attribute__((ext_vector_type(4))) unsigned short u16x4;

#if __has_builtin(__builtin_amdgcn_exp2f)
#define EXP2(x) __builtin_amdgcn_exp2f(x)
#else
#define EXP2(x) exp2f(x)
#endif
#if __has_builtin(__builtin_amdgcn_rcpf)
#define RCP(x) __builtin_amdgcn_rcpf(x)
#else
#define RCP(x) (1.0f / (x))
#endif

__device__ __forceinline__ u16 f2bf(float f) {
    union { float f; unsigned u; } v; v.f = f;
    unsigned u = v.u;
    return (u16)((u + 0x7FFFu + ((u >> 16) & 1u)) >> 16);
}

__device__ __forceinline__ void gload16(const void* g, void* l) {
    __builtin_amdgcn_global_load_lds((const __attribute__((address_space(1))) unsigned int*)g,
                                     (__attribute__((address_space(3))) unsigned int*)l, 16, 0, 0);
}

// ---------------- fused fp32->bf16 conversion + mask->additive ----------------
__global__ void cvt_all(const float4* __restrict__ q, const float4* __restrict__ k,
                        const float4* __restrict__ v, const float4* __restrict__ Wq,
                        const float4* __restrict__ Wk, const float4* __restrict__ Wv,
                        const float4* __restrict__ Wo, const int* __restrict__ mask,
                        u16x4* __restrict__ qb, u16x4* __restrict__ kb, u16x4* __restrict__ vb,
                        u16x4* __restrict__ Wqb, u16x4* __restrict__ Wkb, u16x4* __restrict__ Wvb,
                        u16x4* __restrict__ Wob, float* __restrict__ maskadd) {
    const int z = blockIdx.y;
    if (z == 7) {
        const int i = blockIdx.x * blockDim.x + threadIdx.x;
        if (i < BB * SD) maskadd[i] = (mask[i] != 0) ? 0.f : -1e9f;
        return;
    }
    const float4* src; u16x4* dst; int n4;
    switch (z) {
        case 0: src = q;  dst = qb;  n4 = MROWS * DD / 4; break;
        case 1: src = k;  dst = kb;  n4 = MROWS * DD / 4; break;
        case 2: src = v;  dst = vb;  n4 = MROWS * DD / 4; break;
        case 3: src = Wq; dst = Wqb; n4 = DD * DD / 4; break;
        case 4: src = Wk; dst = Wkb; n4 = DD * DD / 4; break;
        case 5: src = Wv; dst = Wvb; n4 = DD * DD / 4; break;
        default: src = Wo; dst = Wob; n4 = DD * DD / 4; break;
    }
    for (int i = blockIdx.x * blockDim.x + threadIdx.x; i < n4; i += gridDim.x * blockDim.x) {
        float4 f = src[i];
        u16x4 o;
        o.x = f2bf(f.x); o.y = f2bf(f.y); o.z = f2bf(f.z); o.w = f2bf(f.w);
        dst[i] = o;
    }
}

// ---------------- 128x64 GEMM mainloop (BK=64), DOUBLE-BUFFERED single-barrier ----------------
// 48KB LDS -> 3 blocks/CU (used by gemm_qkv, 768 blocks).
__device__ __forceinline__ void gemm_main64(const u16* __restrict__ A, const u16* __restrict__ W,
                                            u16* As, u16* Bs, floatx4 (&acc)[2][4],
                                            int row0, int col0) {
    const int tid = threadIdx.x;
    const int w = tid >> 6, lane = tid & 63, lg = lane >> 4, lr = lane & 15;
    const int lrow = lane >> 3;          // 0..7  (8 rows per 1KB wave segment)
    const int lcol = (lane & 7) * 8;     // element col within 64

    const u16* Abase = A + (row0 + lrow) * KDIM + lcol;
    const u16* Wbase = W + (col0 + lrow) * KDIM + lcol;

    // prologue: stage k0=0 into buf 0
#pragma unroll
    for (int j = 0; j < 4; j++) {
        const int seg = j * 4 + w;
        gload16(Abase + seg * 8 * KDIM, As + seg * 512);
    }
#pragma unroll
    for (int j = 0; j < 2; j++) {
        const int seg = j * 4 + w;
        gload16(Wbase + seg * 8 * KDIM, Bs + seg * 512);
    }
    __syncthreads();

    int buf = 0;
    for (int k0 = 0; k0 < KDIM; k0 += 64) {
        if (k0 + 64 < KDIM) {
            const int nb = buf ^ 1;
#pragma unroll
            for (int j = 0; j < 4; j++) {
                const int seg = j * 4 + w;
                gload16(Abase + seg * 8 * KDIM + k0 + 64, As + nb * 8192 + seg * 512);
            }
#pragma unroll
            for (int j = 0; j < 2; j++) {
                const int seg = j * 4 + w;
                gload16(Wbase + seg * 8 * KDIM + k0 + 64, Bs + nb * 4096 + seg * 512);
            }
        }
        const u16* Asb = As + buf * 8192;
        const u16* Bsb = Bs + buf * 4096;
        short8 af[2][2], bf[4][2];
#pragma unroll
        for (int kk = 0; kk < 2; kk++) {
#pragma unroll
            for (int mi = 0; mi < 2; mi++)
                af[mi][kk] = *(const short8*)&Asb[(w * 32 + mi * 16 + lr) * 64 + kk * 32 + lg * 8];
#pragma unroll
            for (int ni = 0; ni < 4; ni++)
                bf[ni][kk] = *(const short8*)&Bsb[(ni * 16 + lr) * 64 + kk * 32 + lg * 8];
        }
#pragma unroll
        for (int kk = 0; kk < 2; kk++)
#pragma unroll
            for (int mi = 0; mi < 2; mi++)
#pragma unroll
                for (int ni = 0; ni < 4; ni++)
                    acc[mi][ni] = __builtin_amdgcn_mfma_f32_16x16x32_bf16(af[mi][kk], bf[ni][kk], acc[mi][ni], 0, 0, 0);
        __syncthreads();   // drains vmcnt: next buffer staged + all reads of current done
        buf ^= 1;
    }
}

// fused Q/K/V projection, XCD-clustered 1D grid (768 blocks = 3 blocks/CU).
__global__ __launch_bounds__(256) void gemm_qkv(const u16* __restrict__ qb, const u16* __restrict__ kb,
                                                const u16* __restrict__ vb, const u16* __restrict__ Wqb,
                                                const u16* __restrict__ Wkb, const u16* __restrict__ Wvb,
                                                const float* __restrict__ bq, const float* __restrict__ bk,
                                                const float* __restrict__ bv,
                                                u16* __restrict__ Qh, u16* __restrict__ Kf, u16* __restrict__ Vf) {
    __shared__ u16 As[2 * 128 * 64];
    __shared__ u16 Bs[2 * 64 * 64];
    const int id = blockIdx.x;
    const int xcd = id & 7, j = id >> 3;
    const int z = j >> 5, r = j & 31;
    const int by = (xcd << 1) | (r >> 4), bx = r & 15;

    const u16 *A, *W; const float* bias; u16* out; float scale;
    if (z == 0)      { A = qb; W = Wqb; bias = bq; out = Qh; scale = 0.18033688011112042f; }
    else if (z == 1) { A = kb; W = Wkb; bias = bk; out = Kf; scale = 1.f; }
    else             { A = vb; W = Wvb; bias = bv; out = Vf; scale = 1.f; }

    const int row0 = by * 128, col0 = bx * 64;
    floatx4 acc[2][4] = {};
    gemm_main64(A, W, As, Bs, acc, row0, col0);

    const int tid = threadIdx.x;
    const int w = tid >> 6, lane = tid & 63, lg = lane >> 4, lr = lane & 15;
#pragma unroll
    for (int mi = 0; mi < 2; mi++)
#pragma unroll
        for (int ni = 0; ni < 4; ni++) {
            const int col = col0 + ni * 16 + lr;
            const float bv_ = bias[col];
            const int h = col >> 6, dk = col & 63;
#pragma unroll
            for (int rr = 0; rr < 4; rr++) {
                const int row = row0 + w * 32 + mi * 16 + lg * 4 + rr;
                const int b = row >> 10, s = row & 1023;
                const int bh = b * H + h;
                const float val = (acc[mi][ni][rr] + bv_) * scale;
                if (z == 0) {
                    out[(bh * SD + s) * DK + dk] = f2bf(val);
                } else if (z == 1) {
                    out[bh * 65536 + (s >> 4) * 1024 + (dk >> 5) * 512 +
                        ((dk >> 3) & 3) * 128 + (s & 15) * 8 + (dk & 7)] = f2bf(val);
                } else {
                    out[bh * 65536 + (s >> 6) * 4096 + ((dk >> 4) * 2 + ((s >> 5) & 1)) * 512 +
                        ((s >> 3) & 3) * 128 + (dk & 15) * 8 + (s & 7)] = f2bf(val);
                }
            }
        }
}

// ---------------- O-projection: 64x64 tiles, 512 blocks = 2 indep blocks/CU, 8 waves/CU ------
// Old 128x64/256-block version ran at 1 block/CU (1 wave/SIMD): every barrier drain stalled the
// whole CU. 4 waves in 2x2 quadrants (acc[2][2]/wave), 32KB LDS.
__global__ __launch_bounds__(256) void gemm_o(const u16* __restrict__ A, const u16* __restrict__ W,
                                              const float* __restrict__ bias, float* __restrict__ out) {
    __shared__ u16 As[2 * 64 * 64];
    __shared__ u16 Bs[2 * 64 * 64];
    const int id = blockIdx.x;
    const int xcd = id & 7, j = id >> 3;                 // j 0..63
    const int by = (xcd << 2) | (j >> 4), bx = j & 15;   // by 0..31, bx 0..15
    const int row0 = by * 64, col0 = bx * 64;
    const int tid = threadIdx.x;
    const int w = tid >> 6, lane = tid & 63, lg = lane >> 4, lr = lane & 15;
    const int wr = (w >> 1) * 32, wc = (w & 1) * 32;     // wave quadrant (2x2)
    const int lrow = lane >> 3;          // 0..7
    const int lcol = (lane & 7) * 8;

    const u16* Abase = A + (row0 + lrow) * KDIM + lcol;
    const u16* Wbase = W + (col0 + lrow) * KDIM + lcol;

    floatx4 acc[2][2] = {};

    // prologue: 8 A-segs + 8 B-segs, 2 each per wave
#pragma unroll
    for (int j2 = 0; j2 < 2; j2++) {
        const int seg = j2 * 4 + w;
        gload16(Abase + seg * 8 * KDIM, As + seg * 512);
        gload16(Wbase + seg * 8 * KDIM, Bs + seg * 512);
    }
    __syncthreads();

    int buf = 0;
    for (int k0 = 0; k0 < KDIM; k0 += 64) {
        if (k0 + 64 < KDIM) {
            const int nb = buf ^ 1;
#pragma unroll
            for (int j2 = 0; j2 < 2; j2++) {
                const int seg = j2 * 4 + w;
                gload16(Abase + seg * 8 * KDIM + k0 + 64, As + nb * 4096 + seg * 512);
                gload16(Wbase + seg * 8 * KDIM + k0 + 64, Bs + nb * 4096 + seg * 512);
            }
        }
        const u16* Asb = As + buf * 4096;
        const u16* Bsb = Bs + buf * 4096;
        short8 af[2][2], bf[2][2];
#pragma unroll
        for (int kk = 0; kk < 2; kk++) {
#pragma unroll
            for (int mi = 0; mi < 2; mi++)
                af[mi][kk] = *(const short8*)&Asb[(wr + mi * 16 + lr) * 64 + kk * 32 + lg * 8];
#pragma unroll
            for (int ni = 0; ni < 2; ni++)
                bf[ni][kk] = *(const short8*)&Bsb[(wc + ni * 16 + lr) * 64 + kk * 32 + lg * 8];
        }
#pragma unroll
        for (int kk = 0; kk < 2; kk++)
#pragma unroll
            for (int mi = 0; mi < 2; mi++)
#pragma unroll
                for (int ni = 0; ni < 2; ni++)
                    acc[mi][ni] = __builtin_amdgcn_mfma_f32_16x16x32_bf16(af[mi][kk], bf[ni][kk], acc[mi][ni], 0, 0, 0);
        __syncthreads();
        buf ^= 1;
    }

#pragma unroll
    for (int mi = 0; mi < 2; mi++)
#pragma unroll
        for (int ni = 0; ni < 2; ni++) {
            const int col = col0 + wc + ni * 16 + lr;
            const float bv_ = bias[col];
#pragma unroll
            for (int rr = 0; rr < 4; rr++) {
                const int row = row0 + wr + mi * 16 + lg * 4 + rr;
                out[row * DD + col] = acc[mi][ni][rr] + bv_;
            }
        }
}

// ---------------- fused full-KV flash attention: QBLK=64, 4 waves, NSPLIT=1 ----------------
// LDS = 40KB -> 4 blocks/CU (16 waves). T5: setprio(1) around MFMA clusters — 4 desynced
// blocks/CU gives wave-role diversity (m191-positive regime).
__global__ __launch_bounds__(256, 4) void attn_fused(const u16* __restrict__ Qh,
                                                     const u16* __restrict__ Kf,
                                                     const u16* __restrict__ Vf,
                                                     const float* __restrict__ maskadd,
                                                     u16* __restrict__ attn) {
    __shared__ u16 KV[2][8192];        // [buf][ K: 4096 u16 | V: 4096 u16 ] = 16KB/buf
    __shared__ u16 Plds[4 * 16 * 64];  // 8KB, slot-swizzled
    const int id = blockIdx.x;
    const int xcd = id & 7, sblk = id >> 3;
    const int bh = (xcd << 2) | (sblk >> 4);
    const int qx = sblk & 15;
    const int b = bh >> 4, h = bh & 15;
    const int tid = threadIdx.x;
    const int w = tid >> 6, lane = tid & 63;
    const int lg = lane >> 4, lr = lane & 15;
    const int q0 = qx * 64 + w * 16;

    const u16* Qb = Qh + bh * SD * DK;
    const u16* Kb = Kf + bh * 65536;
    const u16* Vb = Vf + bh * 65536;
    const float* mb = maskadd + b * SD;

    short8 aq0 = *(const short8*)&Qb[(q0 + lr) * DK + lg * 8];
    short8 aq1 = *(const short8*)&Qb[(q0 + lr) * DK + 32 + lg * 8];

    floatx4 o[4] = {};
    float lsum[4] = {0.f, 0.f, 0.f, 0.f};

    const int NIT = SD / 64;           // 16
    const int c0 = w * 2, c1 = w * 2 + 1;

    // P read addresses (swizzled): row = lr, slots lg and 4+lg
    const int prd0 = (w << 10) | (lr << 6) | ((lg ^ (lr & 7)) << 3);
    const int prd1 = (w << 10) | (lr << 6) | (((4 + lg) ^ (lr & 7)) << 3);

    gload16(Kb + c0 * 512 + lane * 8, &KV[0][c0 * 512]);
    gload16(Kb + c1 * 512 + lane * 8, &KV[0][c1 * 512]);
    gload16(Vb + c0 * 512 + lane * 8, &KV[0][4096 + c0 * 512]);
    gload16(Vb + c1 * 512 + lane * 8, &KV[0][4096 + c1 * 512]);
    __syncthreads();

    int buf = 0;
    for (int it = 0; it < NIT; ++it) {
        const int kv0 = it * 64;
        if (it + 1 < NIT) {
            const int nxt = (kv0 + 64) * 64;
            gload16(Kb + nxt + c0 * 512 + lane * 8, &KV[buf ^ 1][c0 * 512]);
            gload16(Kb + nxt + c1 * 512 + lane * 8, &KV[buf ^ 1][c1 * 512]);
            gload16(Vb + nxt + c0 * 512 + lane * 8, &KV[buf ^ 1][4096 + c0 * 512]);
            gload16(Vb + nxt + c1 * 512 + lane * 8, &KV[buf ^ 1][4096 + c1 * 512]);
        }
        const u16* Ks = &KV[buf][0];
        const u16* Vs = &KV[buf][4096];
#pragma unroll
        for (int ct = 0; ct < 4; ct++) {
            const float ma = mb[kv0 + ct * 16 + lr];
            short8 bk0 = *(const short8*)&Ks[ct * 1024 + lg * 128 + lr * 8];
            short8 bk1 = *(const short8*)&Ks[ct * 1024 + 512 + lg * 128 + lr * 8];
            floatx4 acc = {ma, ma, ma, ma};
            __builtin_amdgcn_s_setprio(1);
            acc = __builtin_amdgcn_mfma_f32_16x16x32_bf16(aq0, bk0, acc, 0, 0, 0);
            acc = __builtin_amdgcn_mfma_f32_16x16x32_bf16(aq1, bk1, acc, 0, 0, 0);
            __builtin_amdgcn_s_setprio(0);
#pragma unroll
            for (int rr = 0; rr < 4; rr++) {
                const float p = EXP2(acc[rr]);
                lsum[rr] += p;
                const int row = lg * 4 + rr;
                const int slot = (ct * 2 + (lr >> 3)) ^ (row & 7);
                Plds[(w << 10) | (row << 6) | (slot << 3) | (lr & 7)] = f2bf(p);
            }
        }
        // per-wave LDS P buffer: same-wave dependency, compiler inserts lgkmcnt wait
        short8 pa0 = *(const short8*)&Plds[prd0];
        short8 pa1 = *(const short8*)&Plds[prd1];
        __builtin_amdgcn_s_setprio(1);
#pragma unroll
        for (int cd = 0; cd < 4; cd++) {
            short8 vb0 = *(const short8*)&Vs[cd * 1024 + lg * 128 + lr * 8];
            short8 vb1 = *(const short8*)&Vs[cd * 1024 + 512 + lg * 128 + lr * 8];
            o[cd] = __builtin_amdgcn_mfma_f32_16x16x32_bf16(pa0, vb0, o[cd], 0, 0, 0);
            o[cd] = __builtin_amdgcn_mfma_f32_16x16x32_bf16(pa1, vb1, o[cd], 0, 0, 0);
        }
        __builtin_amdgcn_s_setprio(0);
        __syncthreads();   // staging complete + all reads of buf done
        buf ^= 1;
    }

#pragma unroll
    for (int rr = 0; rr < 4; rr++) {
        lsum[rr] += __shfl_xor(lsum[rr], 1);
        lsum[rr] += __shfl_xor(lsum[rr], 2);
        lsum[rr] += __shfl_xor(lsum[rr], 4);
        lsum[rr] += __shfl_xor(lsum[rr], 8);
    }

#pragma unroll
    for (int rr = 0; rr < 4; rr++) {
        const float inv = RCP(lsum[rr]);
        const int row = q0 + lg * 4 + rr;
#pragma unroll
        for (int cd = 0; cd < 4; cd++) {
            const int d = h * 64 + cd * 16 + lr;
            attn[(b * SD + row) * DD + d] = f2bf(o[cd][rr] * inv);
        }
    }
}

extern "C" void kernel_launch(void* const* d_in, const int* in_sizes, int n_in,
                              void* d_out, int out_size, void* d_ws, size_t ws_size,
                              hipStream_t stream) {
    const float* q  = (const float*)d_in[0];
    const float* k  = (const float*)d_in[1];
    const float* v  = (const float*)d_in[2];
    const int* mask = (const int*)d_in[3];
    const float* Wq = (const float*)d_in[4];
    const float* bq = (const float*)d_in[5];
    const float* Wk = (const float*)d_in[6];
    const float* bk = (const float*)d_in[7];
    const float* Wv = (const float*)d_in[8];
    const float* bv = (const float*)d_in[9];
    const float* Wo = (const float*)d_in[10];
    const float* bo = (const float*)d_in[11];
    float* out = (float*)d_out;

    u16* p = (u16*)d_ws;
    u16* qb  = p; p += MROWS * DD;
    u16* kb  = p; p += MROWS * DD;
    u16* vb  = p; p += MROWS * DD;
    u16* Wqb = p; p += DD * DD;
    u16* Wkb = p; p += DD * DD;
    u16* Wvb = p; p += DD * DD;
    u16* Wob = p; p += DD * DD;
    u16* Qh  = p; p += MROWS * DD;
    u16* Kf  = p; p += MROWS * DD;
    u16* Vf  = p; p += MROWS * DD;
    u16* attn = p; p += MROWS * DD;
    float* maskadd = (float*)p;

    cvt_all<<<dim3(512, 8), 256, 0, stream>>>((const float4*)q, (const float4*)k, (const float4*)v,
                                              (const float4*)Wq, (const float4*)Wk, (const float4*)Wv,
                                              (const float4*)Wo, mask,
                                              (u16x4*)qb, (u16x4*)kb, (u16x4*)vb,
                                              (u16x4*)Wqb, (u16x4*)Wkb, (u16x4*)Wvb, (u16x4*)Wob,
                                              maskadd);

    gemm_qkv<<<768, 256, 0, stream>>>(qb, kb, vb, Wqb, Wkb, Wvb, bq, bk, bv, Qh, Kf, Vf);

    attn_fused<<<512, 256, 0, stream>>>(Qh, Kf, Vf, maskadd, attn);

    gemm_o<<<512, 256, 0, stream>>>(attn, Wob, bo, out);
}

// Round 5
// 85.404 us; speedup vs baseline: 1.0245x; 1.0245x over previous
//
#include <hip/hip_runtime.h>

#define H 16
#define DK 64
#define SD 1024
#define DD 1024
#define BB 2
#define MROWS (BB * SD)   // 2048
#define KDIM 1024

typedef __attribute__((ext_vector_type(8))) short short8;
typedef __attribute__((ext_vector_type(4))) float floatx4;
typedef unsigned short u16;
typedef __attribute__((ext_vector_type(4))) unsigned short u16x4;

#if __has_builtin(__builtin_amdgcn_exp2f)
#define EXP2(x) __builtin_amdgcn_exp2f(x)
#else
#define EXP2(x) exp2f(x)
#endif
#if __has_builtin(__builtin_amdgcn_rcpf)
#define RCP(x) __builtin_amdgcn_rcpf(x)
#else
#define RCP(x) (1.0f / (x))
#endif

__device__ __forceinline__ u16 f2bf(float f) {
    union { float f; unsigned u; } v; v.f = f;
    unsigned u = v.u;
    return (u16)((u + 0x7FFFu + ((u >> 16) & 1u)) >> 16);
}

__device__ __forceinline__ void gload16(const void* g, void* l) {
    __builtin_amdgcn_global_load_lds((const __attribute__((address_space(1))) unsigned int*)g,
                                     (__attribute__((address_space(3))) unsigned int*)l, 16, 0, 0);
}

// ---------------- fused fp32->bf16 conversion + mask->additive ----------------
__global__ void cvt_all(const float4* __restrict__ q, const float4* __restrict__ k,
                        const float4* __restrict__ v, const float4* __restrict__ Wq,
                        const float4* __restrict__ Wk, const float4* __restrict__ Wv,
                        const float4* __restrict__ Wo, const int* __restrict__ mask,
                        u16x4* __restrict__ qb, u16x4* __restrict__ kb, u16x4* __restrict__ vb,
                        u16x4* __restrict__ Wqb, u16x4* __restrict__ Wkb, u16x4* __restrict__ Wvb,
                        u16x4* __restrict__ Wob, float* __restrict__ maskadd) {
    const int z = blockIdx.y;
    if (z == 7) {
        const int i = blockIdx.x * blockDim.x + threadIdx.x;
        if (i < BB * SD) maskadd[i] = (mask[i] != 0) ? 0.f : -1e9f;
        return;
    }
    const float4* src; u16x4* dst; int n4;
    switch (z) {
        case 0: src = q;  dst = qb;  n4 = MROWS * DD / 4; break;
        case 1: src = k;  dst = kb;  n4 = MROWS * DD / 4; break;
        case 2: src = v;  dst = vb;  n4 = MROWS * DD / 4; break;
        case 3: src = Wq; dst = Wqb; n4 = DD * DD / 4; break;
        case 4: src = Wk; dst = Wkb; n4 = DD * DD / 4; break;
        case 5: src = Wv; dst = Wvb; n4 = DD * DD / 4; break;
        default: src = Wo; dst = Wob; n4 = DD * DD / 4; break;
    }
    for (int i = blockIdx.x * blockDim.x + threadIdx.x; i < n4; i += gridDim.x * blockDim.x) {
        float4 f = src[i];
        u16x4 o;
        o.x = f2bf(f.x); o.y = f2bf(f.y); o.z = f2bf(f.z); o.w = f2bf(f.w);
        dst[i] = o;
    }
}

// ---------------- 128x64 GEMM mainloop (BK=64), DOUBLE-BUFFERED single-barrier ----------------
// 48KB LDS -> 3 blocks/CU. NOTE (r4): do NOT shrink the wave tile below 16 MFMA/barrier —
// the 128B-stride LDS reads are 16-way conflicted (latent in all our GEMMs); a thinner MFMA
// layer stops hiding the conflict cost (r4 gemm_o 64x64: 3.1M conflict cycles, regressed).
__device__ __forceinline__ void gemm_main64(const u16* __restrict__ A, const u16* __restrict__ W,
                                            u16* As, u16* Bs, floatx4 (&acc)[2][4],
                                            int row0, int col0) {
    const int tid = threadIdx.x;
    const int w = tid >> 6, lane = tid & 63, lg = lane >> 4, lr = lane & 15;
    const int lrow = lane >> 3;          // 0..7  (8 rows per 1KB wave segment)
    const int lcol = (lane & 7) * 8;     // element col within 64

    const u16* Abase = A + (row0 + lrow) * KDIM + lcol;
    const u16* Wbase = W + (col0 + lrow) * KDIM + lcol;

    // prologue: stage k0=0 into buf 0
#pragma unroll
    for (int j = 0; j < 4; j++) {
        const int seg = j * 4 + w;
        gload16(Abase + seg * 8 * KDIM, As + seg * 512);
    }
#pragma unroll
    for (int j = 0; j < 2; j++) {
        const int seg = j * 4 + w;
        gload16(Wbase + seg * 8 * KDIM, Bs + seg * 512);
    }
    __syncthreads();

    int buf = 0;
    for (int k0 = 0; k0 < KDIM; k0 += 64) {
        if (k0 + 64 < KDIM) {
            const int nb = buf ^ 1;
#pragma unroll
            for (int j = 0; j < 4; j++) {
                const int seg = j * 4 + w;
                gload16(Abase + seg * 8 * KDIM + k0 + 64, As + nb * 8192 + seg * 512);
            }
#pragma unroll
            for (int j = 0; j < 2; j++) {
                const int seg = j * 4 + w;
                gload16(Wbase + seg * 8 * KDIM + k0 + 64, Bs + nb * 4096 + seg * 512);
            }
        }
        const u16* Asb = As + buf * 8192;
        const u16* Bsb = Bs + buf * 4096;
        short8 af[2][2], bf[4][2];
#pragma unroll
        for (int kk = 0; kk < 2; kk++) {
#pragma unroll
            for (int mi = 0; mi < 2; mi++)
                af[mi][kk] = *(const short8*)&Asb[(w * 32 + mi * 16 + lr) * 64 + kk * 32 + lg * 8];
#pragma unroll
            for (int ni = 0; ni < 4; ni++)
                bf[ni][kk] = *(const short8*)&Bsb[(ni * 16 + lr) * 64 + kk * 32 + lg * 8];
        }
#pragma unroll
        for (int kk = 0; kk < 2; kk++)
#pragma unroll
            for (int mi = 0; mi < 2; mi++)
#pragma unroll
                for (int ni = 0; ni < 4; ni++)
                    acc[mi][ni] = __builtin_amdgcn_mfma_f32_16x16x32_bf16(af[mi][kk], bf[ni][kk], acc[mi][ni], 0, 0, 0);
        __syncthreads();   // drains vmcnt: next buffer staged + all reads of current done
        buf ^= 1;
    }
}

// fused Q/K/V projection, XCD-clustered 1D grid (768 blocks = 3 blocks/CU).
__global__ __launch_bounds__(256) void gemm_qkv(const u16* __restrict__ qb, const u16* __restrict__ kb,
                                                const u16* __restrict__ vb, const u16* __restrict__ Wqb,
                                                const u16* __restrict__ Wkb, const u16* __restrict__ Wvb,
                                                const float* __restrict__ bq, const float* __restrict__ bk,
                                                const float* __restrict__ bv,
                                                u16* __restrict__ Qh, u16* __restrict__ Kf, u16* __restrict__ Vf) {
    __shared__ u16 As[2 * 128 * 64];
    __shared__ u16 Bs[2 * 64 * 64];
    const int id = blockIdx.x;
    const int xcd = id & 7, j = id >> 3;
    const int z = j >> 5, r = j & 31;
    const int by = (xcd << 1) | (r >> 4), bx = r & 15;

    const u16 *A, *W; const float* bias; u16* out; float scale;
    if (z == 0)      { A = qb; W = Wqb; bias = bq; out = Qh; scale = 0.18033688011112042f; }
    else if (z == 1) { A = kb; W = Wkb; bias = bk; out = Kf; scale = 1.f; }
    else             { A = vb; W = Wvb; bias = bv; out = Vf; scale = 1.f; }

    const int row0 = by * 128, col0 = bx * 64;
    floatx4 acc[2][4] = {};
    gemm_main64(A, W, As, Bs, acc, row0, col0);

    const int tid = threadIdx.x;
    const int w = tid >> 6, lane = tid & 63, lg = lane >> 4, lr = lane & 15;
#pragma unroll
    for (int mi = 0; mi < 2; mi++)
#pragma unroll
        for (int ni = 0; ni < 4; ni++) {
            const int col = col0 + ni * 16 + lr;
            const float bv_ = bias[col];
            const int h = col >> 6, dk = col & 63;
#pragma unroll
            for (int rr = 0; rr < 4; rr++) {
                const int row = row0 + w * 32 + mi * 16 + lg * 4 + rr;
                const int b = row >> 10, s = row & 1023;
                const int bh = b * H + h;
                const float val = (acc[mi][ni][rr] + bv_) * scale;
                if (z == 0) {
                    out[(bh * SD + s) * DK + dk] = f2bf(val);
                } else if (z == 1) {
                    out[bh * 65536 + (s >> 4) * 1024 + (dk >> 5) * 512 +
                        ((dk >> 3) & 3) * 128 + (s & 15) * 8 + (dk & 7)] = f2bf(val);
                } else {
                    out[bh * 65536 + (s >> 6) * 4096 + ((dk >> 4) * 2 + ((s >> 5) & 1)) * 512 +
                        ((s >> 3) & 3) * 128 + (dk & 15) * 8 + (s & 7)] = f2bf(val);
                }
            }
        }
}

// ---------------- O-projection, XCD-clustered 1D grid (256 blocks, 128x64 tile) ----------------
// r4 lesson: 64x64/512-block variant regressed (thin MFMA layer exposes LDS conflicts). Keep.
__global__ __launch_bounds__(256) void gemm_o(const u16* __restrict__ A, const u16* __restrict__ W,
                                              const float* __restrict__ bias, float* __restrict__ out) {
    __shared__ u16 As[2 * 128 * 64];
    __shared__ u16 Bs[2 * 64 * 64];
    const int id = blockIdx.x;
    const int xcd = id & 7, j = id >> 3;
    const int by = (xcd << 1) | (j >> 4), bx = j & 15;
    const int row0 = by * 128, col0 = bx * 64;
    floatx4 acc[2][4] = {};
    gemm_main64(A, W, As, Bs, acc, row0, col0);

    const int tid = threadIdx.x;
    const int w = tid >> 6, lane = tid & 63, lg = lane >> 4, lr = lane & 15;
#pragma unroll
    for (int mi = 0; mi < 2; mi++)
#pragma unroll
        for (int ni = 0; ni < 4; ni++) {
            const int col = col0 + ni * 16 + lr;
            const float bv_ = bias[col];
#pragma unroll
            for (int rr = 0; rr < 4; rr++) {
                const int row = row0 + w * 32 + mi * 16 + lg * 4 + rr;
                out[row * DD + col] = acc[mi][ni][rr] + bv_;
            }
        }
}

// ---------------- fused full-KV flash attention: QBLK=64, 4 waves, NSPLIT=1 ----------------
// LDS = 40KB -> 4 blocks/CU (16 waves). T5 setprio kept: this round is its clean A/B vs r3.
__global__ __launch_bounds__(256, 4) void attn_fused(const u16* __restrict__ Qh,
                                                     const u16* __restrict__ Kf,
                                                     const u16* __restrict__ Vf,
                                                     const float* __restrict__ maskadd,
                                                     u16* __restrict__ attn) {
    __shared__ u16 KV[2][8192];        // [buf][ K: 4096 u16 | V: 4096 u16 ] = 16KB/buf
    __shared__ u16 Plds[4 * 16 * 64];  // 8KB, slot-swizzled
    const int id = blockIdx.x;
    const int xcd = id & 7, sblk = id >> 3;
    const int bh = (xcd << 2) | (sblk >> 4);
    const int qx = sblk & 15;
    const int b = bh >> 4, h = bh & 15;
    const int tid = threadIdx.x;
    const int w = tid >> 6, lane = tid & 63;
    const int lg = lane >> 4, lr = lane & 15;
    const int q0 = qx * 64 + w * 16;

    const u16* Qb = Qh + bh * SD * DK;
    const u16* Kb = Kf + bh * 65536;
    const u16* Vb = Vf + bh * 65536;
    const float* mb = maskadd + b * SD;

    short8 aq0 = *(const short8*)&Qb[(q0 + lr) * DK + lg * 8];
    short8 aq1 = *(const short8*)&Qb[(q0 + lr) * DK + 32 + lg * 8];

    floatx4 o[4] = {};
    float lsum[4] = {0.f, 0.f, 0.f, 0.f};

    const int NIT = SD / 64;           // 16
    const int c0 = w * 2, c1 = w * 2 + 1;

    // P read addresses (swizzled): row = lr, slots lg and 4+lg
    const int prd0 = (w << 10) | (lr << 6) | ((lg ^ (lr & 7)) << 3);
    const int prd1 = (w << 10) | (lr << 6) | (((4 + lg) ^ (lr & 7)) << 3);

    gload16(Kb + c0 * 512 + lane * 8, &KV[0][c0 * 512]);
    gload16(Kb + c1 * 512 + lane * 8, &KV[0][c1 * 512]);
    gload16(Vb + c0 * 512 + lane * 8, &KV[0][4096 + c0 * 512]);
    gload16(Vb + c1 * 512 + lane * 8, &KV[0][4096 + c1 * 512]);
    __syncthreads();

    int buf = 0;
    for (int it = 0; it < NIT; ++it) {
        const int kv0 = it * 64;
        if (it + 1 < NIT) {
            const int nxt = (kv0 + 64) * 64;
            gload16(Kb + nxt + c0 * 512 + lane * 8, &KV[buf ^ 1][c0 * 512]);
            gload16(Kb + nxt + c1 * 512 + lane * 8, &KV[buf ^ 1][c1 * 512]);
            gload16(Vb + nxt + c0 * 512 + lane * 8, &KV[buf ^ 1][4096 + c0 * 512]);
            gload16(Vb + nxt + c1 * 512 + lane * 8, &KV[buf ^ 1][4096 + c1 * 512]);
        }
        const u16* Ks = &KV[buf][0];
        const u16* Vs = &KV[buf][4096];
#pragma unroll
        for (int ct = 0; ct < 4; ct++) {
            const float ma = mb[kv0 + ct * 16 + lr];
            short8 bk0 = *(const short8*)&Ks[ct * 1024 + lg * 128 + lr * 8];
            short8 bk1 = *(const short8*)&Ks[ct * 1024 + 512 + lg * 128 + lr * 8];
            floatx4 acc = {ma, ma, ma, ma};
            __builtin_amdgcn_s_setprio(1);
            acc = __builtin_amdgcn_mfma_f32_16x16x32_bf16(aq0, bk0, acc, 0, 0, 0);
            acc = __builtin_amdgcn_mfma_f32_16x16x32_bf16(aq1, bk1, acc, 0, 0, 0);
            __builtin_amdgcn_s_setprio(0);
#pragma unroll
            for (int rr = 0; rr < 4; rr++) {
                const float p = EXP2(acc[rr]);
                lsum[rr] += p;
                const int row = lg * 4 + rr;
                const int slot = (ct * 2 + (lr >> 3)) ^ (row & 7);
                Plds[(w << 10) | (row << 6) | (slot << 3) | (lr & 7)] = f2bf(p);
            }
        }
        // per-wave LDS P buffer: same-wave dependency, compiler inserts lgkmcnt wait
        short8 pa0 = *(const short8*)&Plds[prd0];
        short8 pa1 = *(const short8*)&Plds[prd1];
        __builtin_amdgcn_s_setprio(1);
#pragma unroll
        for (int cd = 0; cd < 4; cd++) {
            short8 vb0 = *(const short8*)&Vs[cd * 1024 + lg * 128 + lr * 8];
            short8 vb1 = *(const short8*)&Vs[cd * 1024 + 512 + lg * 128 + lr * 8];
            o[cd] = __builtin_amdgcn_mfma_f32_16x16x32_bf16(pa0, vb0, o[cd], 0, 0, 0);
            o[cd] = __builtin_amdgcn_mfma_f32_16x16x32_bf16(pa1, vb1, o[cd], 0, 0, 0);
        }
        __builtin_amdgcn_s_setprio(0);
        __syncthreads();   // staging complete + all reads of buf done
        buf ^= 1;
    }

#pragma unroll
    for (int rr = 0; rr < 4; rr++) {
        lsum[rr] += __shfl_xor(lsum[rr], 1);
        lsum[rr] += __shfl_xor(lsum[rr], 2);
        lsum[rr] += __shfl_xor(lsum[rr], 4);
        lsum[rr] += __shfl_xor(lsum[rr], 8);
    }

#pragma unroll
    for (int rr = 0; rr < 4; rr++) {
        const float inv = RCP(lsum[rr]);
        const int row = q0 + lg * 4 + rr;
#pragma unroll
        for (int cd = 0; cd < 4; cd++) {
            const int d = h * 64 + cd * 16 + lr;
            attn[(b * SD + row) * DD + d] = f2bf(o[cd][rr] * inv);
        }
    }
}

extern "C" void kernel_launch(void* const* d_in, const int* in_sizes, int n_in,
                              void* d_out, int out_size, void* d_ws, size_t ws_size,
                              hipStream_t stream) {
    const float* q  = (const float*)d_in[0];
    const float* k  = (const float*)d_in[1];
    const float* v  = (const float*)d_in[2];
    const int* mask = (const int*)d_in[3];
    const float* Wq = (const float*)d_in[4];
    const float* bq = (const float*)d_in[5];
    const float* Wk = (const float*)d_in[6];
    const float* bk = (const float*)d_in[7];
    const float* Wv = (const float*)d_in[8];
    const float* bv = (const float*)d_in[9];
    const float* Wo = (const float*)d_in[10];
    const float* bo = (const float*)d_in[11];
    float* out = (float*)d_out;

    u16* p = (u16*)d_ws;
    u16* qb  = p; p += MROWS * DD;
    u16* kb  = p; p += MROWS * DD;
    u16* vb  = p; p += MROWS * DD;
    u16* Wqb = p; p += DD * DD;
    u16* Wkb = p; p += DD * DD;
    u16* Wvb = p; p += DD * DD;
    u16* Wob = p; p += DD * DD;
    u16* Qh  = p; p += MROWS * DD;
    u16* Kf  = p; p += MROWS * DD;
    u16* Vf  = p; p += MROWS * DD;
    u16* attn = p; p += MROWS * DD;
    float* maskadd = (float*)p;

    cvt_all<<<dim3(512, 8), 256, 0, stream>>>((const float4*)q, (const float4*)k, (const float4*)v,
                                              (const float4*)Wq, (const float4*)Wk, (const float4*)Wv,
                                              (const float4*)Wo, mask,
                                              (u16x4*)qb, (u16x4*)kb, (u16x4*)vb,
                                              (u16x4*)Wqb, (u16x4*)Wkb, (u16x4*)Wvb, (u16x4*)Wob,
                                              maskadd);

    gemm_qkv<<<768, 256, 0, stream>>>(qb, kb, vb, Wqb, Wkb, Wvb, bq, bk, bv, Qh, Kf, Vf);

    attn_fused<<<512, 256, 0, stream>>>(Qh, Kf, Vf, maskadd, attn);

    gemm_o<<<256, 256, 0, stream>>>(attn, Wob, bo, out);
}

// Round 6
// 83.232 us; speedup vs baseline: 1.0512x; 1.0261x over previous
//
#include <hip/hip_runtime.h>

#define H 16
#define DK 64
#define SD 1024
#define DD 1024
#define BB 2
#define MROWS (BB * SD)   // 2048
#define KDIM 1024

typedef __attribute__((ext_vector_type(8))) short short8;
typedef __attribute__((ext_vector_type(4))) float floatx4;
typedef unsigned short u16;
typedef __attribute__((ext_vector_type(4))) unsigned short u16x4;

#if __has_builtin(__builtin_amdgcn_exp2f)
#define EXP2(x) __builtin_amdgcn_exp2f(x)
#else
#define EXP2(x) exp2f(x)
#endif
#if __has_builtin(__builtin_amdgcn_rcpf)
#define RCP(x) __builtin_amdgcn_rcpf(x)
#else
#define RCP(x) (1.0f / (x))
#endif

__device__ __forceinline__ u16 f2bf(float f) {
    union { float f; unsigned u; } v; v.f = f;
    unsigned u = v.u;
    return (u16)((u + 0x7FFFu + ((u >> 16) & 1u)) >> 16);
}

__device__ __forceinline__ void gload16(const void* g, void* l) {
    __builtin_amdgcn_global_load_lds((const __attribute__((address_space(1))) unsigned int*)g,
                                     (__attribute__((address_space(3))) unsigned int*)l, 16, 0, 0);
}

// ---------------- fused fp32->bf16 conversion + mask->additive ----------------
__global__ void cvt_all(const float4* __restrict__ q, const float4* __restrict__ k,
                        const float4* __restrict__ v, const float4* __restrict__ Wq,
                        const float4* __restrict__ Wk, const float4* __restrict__ Wv,
                        const float4* __restrict__ Wo, const int* __restrict__ mask,
                        u16x4* __restrict__ qb, u16x4* __restrict__ kb, u16x4* __restrict__ vb,
                        u16x4* __restrict__ Wqb, u16x4* __restrict__ Wkb, u16x4* __restrict__ Wvb,
                        u16x4* __restrict__ Wob, float* __restrict__ maskadd) {
    const int z = blockIdx.y;
    if (z == 7) {
        const int i = blockIdx.x * blockDim.x + threadIdx.x;
        if (i < BB * SD) maskadd[i] = (mask[i] != 0) ? 0.f : -1e9f;
        return;
    }
    const float4* src; u16x4* dst; int n4;
    switch (z) {
        case 0: src = q;  dst = qb;  n4 = MROWS * DD / 4; break;
        case 1: src = k;  dst = kb;  n4 = MROWS * DD / 4; break;
        case 2: src = v;  dst = vb;  n4 = MROWS * DD / 4; break;
        case 3: src = Wq; dst = Wqb; n4 = DD * DD / 4; break;
        case 4: src = Wk; dst = Wkb; n4 = DD * DD / 4; break;
        case 5: src = Wv; dst = Wvb; n4 = DD * DD / 4; break;
        default: src = Wo; dst = Wob; n4 = DD * DD / 4; break;
    }
    for (int i = blockIdx.x * blockDim.x + threadIdx.x; i < n4; i += gridDim.x * blockDim.x) {
        float4 f = src[i];
        u16x4 o;
        o.x = f2bf(f.x); o.y = f2bf(f.y); o.z = f2bf(f.z); o.w = f2bf(f.w);
        dst[i] = o;
    }
}

// ---------------- 128x64 GEMM mainloop (BK=64), counted-vmcnt double-buffer (T4-lite) ---------
// Old: one __syncthreads/iter = full vmcnt(0) drain of the JUST-ISSUED prefetch (exposed load
// latency every tile). New: per-wave s_waitcnt vmcnt(6) (own prev-tile loads only) + raw
// s_barrier pair; next tile's 6 loads stay in flight across the barrier.
// Hazards: RAW covered by per-wave vmcnt BEFORE barrier A (disjoint segments per wave);
// WAR covered by barrier B after MFMA (ds_reads complete before MFMA via lgkmcnt);
// sched_barrier(0) after each barrier pins ds_read below it (rule #18).
__device__ __forceinline__ void gemm_main64(const u16* __restrict__ A, const u16* __restrict__ W,
                                            u16* As, u16* Bs, floatx4 (&acc)[2][4],
                                            int row0, int col0) {
    const int tid = threadIdx.x;
    const int w = tid >> 6, lane = tid & 63, lg = lane >> 4, lr = lane & 15;
    const int lrow = lane >> 3;          // 0..7  (8 rows per 1KB wave segment)
    const int lcol = (lane & 7) * 8;     // element col within 64

    const u16* Abase = A + (row0 + lrow) * KDIM + lcol;
    const u16* Wbase = W + (col0 + lrow) * KDIM + lcol;

    // prologue: stage tile 0 into buf 0 (6 loads/wave)
#pragma unroll
    for (int j = 0; j < 4; j++) {
        const int seg = j * 4 + w;
        gload16(Abase + seg * 8 * KDIM, As + seg * 512);
    }
#pragma unroll
    for (int j = 0; j < 2; j++) {
        const int seg = j * 4 + w;
        gload16(Wbase + seg * 8 * KDIM, Bs + seg * 512);
    }

    int buf = 0;
    for (int k0 = 0; k0 < KDIM; k0 += 64) {
        if (k0 + 64 < KDIM) {
            const int nb = buf ^ 1;
#pragma unroll
            for (int j = 0; j < 4; j++) {
                const int seg = j * 4 + w;
                gload16(Abase + seg * 8 * KDIM + k0 + 64, As + nb * 8192 + seg * 512);
            }
#pragma unroll
            for (int j = 0; j < 2; j++) {
                const int seg = j * 4 + w;
                gload16(Wbase + seg * 8 * KDIM + k0 + 64, Bs + nb * 4096 + seg * 512);
            }
            asm volatile("s_waitcnt vmcnt(6)" ::: "memory");   // own tile-t loads landed
        } else {
            asm volatile("s_waitcnt vmcnt(0)" ::: "memory");   // last tile: full drain
        }
        __builtin_amdgcn_s_barrier();          // A: all waves' tile-t staging complete
        __builtin_amdgcn_sched_barrier(0);

        const u16* Asb = As + buf * 8192;
        const u16* Bsb = Bs + buf * 4096;
        short8 af[2][2], bf[4][2];
#pragma unroll
        for (int kk = 0; kk < 2; kk++) {
#pragma unroll
            for (int mi = 0; mi < 2; mi++)
                af[mi][kk] = *(const short8*)&Asb[(w * 32 + mi * 16 + lr) * 64 + kk * 32 + lg * 8];
#pragma unroll
            for (int ni = 0; ni < 4; ni++)
                bf[ni][kk] = *(const short8*)&Bsb[(ni * 16 + lr) * 64 + kk * 32 + lg * 8];
        }
#pragma unroll
        for (int kk = 0; kk < 2; kk++)
#pragma unroll
            for (int mi = 0; mi < 2; mi++)
#pragma unroll
                for (int ni = 0; ni < 4; ni++)
                    acc[mi][ni] = __builtin_amdgcn_mfma_f32_16x16x32_bf16(af[mi][kk], bf[ni][kk], acc[mi][ni], 0, 0, 0);

        asm volatile("s_waitcnt lgkmcnt(0)" ::: "memory");  // all ds_reads of buf retired
        __builtin_amdgcn_s_barrier();          // B: safe to overwrite buf next iter
        __builtin_amdgcn_sched_barrier(0);
        buf ^= 1;
    }
}

// fused Q/K/V projection, XCD-clustered 1D grid (768 blocks = 3 blocks/CU).
__global__ __launch_bounds__(256) void gemm_qkv(const u16* __restrict__ qb, const u16* __restrict__ kb,
                                                const u16* __restrict__ vb, const u16* __restrict__ Wqb,
                                                const u16* __restrict__ Wkb, const u16* __restrict__ Wvb,
                                                const float* __restrict__ bq, const float* __restrict__ bk,
                                                const float* __restrict__ bv,
                                                u16* __restrict__ Qh, u16* __restrict__ Kf, u16* __restrict__ Vf) {
    __shared__ u16 As[2 * 128 * 64];
    __shared__ u16 Bs[2 * 64 * 64];
    const int id = blockIdx.x;
    const int xcd = id & 7, j = id >> 3;
    const int z = j >> 5, r = j & 31;
    const int by = (xcd << 1) | (r >> 4), bx = r & 15;

    const u16 *A, *W; const float* bias; u16* out; float scale;
    if (z == 0)      { A = qb; W = Wqb; bias = bq; out = Qh; scale = 0.18033688011112042f; }
    else if (z == 1) { A = kb; W = Wkb; bias = bk; out = Kf; scale = 1.f; }
    else             { A = vb; W = Wvb; bias = bv; out = Vf; scale = 1.f; }

    const int row0 = by * 128, col0 = bx * 64;
    floatx4 acc[2][4] = {};
    gemm_main64(A, W, As, Bs, acc, row0, col0);

    const int tid = threadIdx.x;
    const int w = tid >> 6, lane = tid & 63, lg = lane >> 4, lr = lane & 15;
#pragma unroll
    for (int mi = 0; mi < 2; mi++)
#pragma unroll
        for (int ni = 0; ni < 4; ni++) {
            const int col = col0 + ni * 16 + lr;
            const float bv_ = bias[col];
            const int h = col >> 6, dk = col & 63;
#pragma unroll
            for (int rr = 0; rr < 4; rr++) {
                const int row = row0 + w * 32 + mi * 16 + lg * 4 + rr;
                const int b = row >> 10, s = row & 1023;
                const int bh = b * H + h;
                const float val = (acc[mi][ni][rr] + bv_) * scale;
                if (z == 0) {
                    out[(bh * SD + s) * DK + dk] = f2bf(val);
                } else if (z == 1) {
                    out[bh * 65536 + (s >> 4) * 1024 + (dk >> 5) * 512 +
                        ((dk >> 3) & 3) * 128 + (s & 15) * 8 + (dk & 7)] = f2bf(val);
                } else {
                    out[bh * 65536 + (s >> 6) * 4096 + ((dk >> 4) * 2 + ((s >> 5) & 1)) * 512 +
                        ((s >> 3) & 3) * 128 + (dk & 15) * 8 + (s & 7)] = f2bf(val);
                }
            }
        }
}

// ---------------- O-projection, XCD-clustered 1D grid (256 blocks, 128x64 tile) ----------------
// r4 lesson: 64x64/512-block variant regressed (thin MFMA layer exposes LDS conflicts). Keep.
__global__ __launch_bounds__(256) void gemm_o(const u16* __restrict__ A, const u16* __restrict__ W,
                                              const float* __restrict__ bias, float* __restrict__ out) {
    __shared__ u16 As[2 * 128 * 64];
    __shared__ u16 Bs[2 * 64 * 64];
    const int id = blockIdx.x;
    const int xcd = id & 7, j = id >> 3;
    const int by = (xcd << 1) | (j >> 4), bx = j & 15;
    const int row0 = by * 128, col0 = bx * 64;
    floatx4 acc[2][4] = {};
    gemm_main64(A, W, As, Bs, acc, row0, col0);

    const int tid = threadIdx.x;
    const int w = tid >> 6, lane = tid & 63, lg = lane >> 4, lr = lane & 15;
#pragma unroll
    for (int mi = 0; mi < 2; mi++)
#pragma unroll
        for (int ni = 0; ni < 4; ni++) {
            const int col = col0 + ni * 16 + lr;
            const float bv_ = bias[col];
#pragma unroll
            for (int rr = 0; rr < 4; rr++) {
                const int row = row0 + w * 32 + mi * 16 + lg * 4 + rr;
                out[row * DD + col] = acc[mi][ni][rr] + bv_;
            }
        }
}

// ---------------- fused full-KV flash attention: QBLK=64, 4 waves, NSPLIT=1 ----------------
// LDS = 40KB -> 4 blocks/CU (16 waves). r5 A/B: setprio was -3.2us (lockstep waves, m190
// regime) — removed; back to exact r3 structure.
__global__ __launch_bounds__(256, 4) void attn_fused(const u16* __restrict__ Qh,
                                                     const u16* __restrict__ Kf,
                                                     const u16* __restrict__ Vf,
                                                     const float* __restrict__ maskadd,
                                                     u16* __restrict__ attn) {
    __shared__ u16 KV[2][8192];        // [buf][ K: 4096 u16 | V: 4096 u16 ] = 16KB/buf
    __shared__ u16 Plds[4 * 16 * 64];  // 8KB, slot-swizzled
    const int id = blockIdx.x;
    const int xcd = id & 7, sblk = id >> 3;
    const int bh = (xcd << 2) | (sblk >> 4);
    const int qx = sblk & 15;
    const int b = bh >> 4, h = bh & 15;
    const int tid = threadIdx.x;
    const int w = tid >> 6, lane = tid & 63;
    const int lg = lane >> 4, lr = lane & 15;
    const int q0 = qx * 64 + w * 16;

    const u16* Qb = Qh + bh * SD * DK;
    const u16* Kb = Kf + bh * 65536;
    const u16* Vb = Vf + bh * 65536;
    const float* mb = maskadd + b * SD;

    short8 aq0 = *(const short8*)&Qb[(q0 + lr) * DK + lg * 8];
    short8 aq1 = *(const short8*)&Qb[(q0 + lr) * DK + 32 + lg * 8];

    floatx4 o[4] = {};
    float lsum[4] = {0.f, 0.f, 0.f, 0.f};

    const int NIT = SD / 64;           // 16
    const int c0 = w * 2, c1 = w * 2 + 1;

    // P read addresses (swizzled): row = lr, slots lg and 4+lg
    const int prd0 = (w << 10) | (lr << 6) | ((lg ^ (lr & 7)) << 3);
    const int prd1 = (w << 10) | (lr << 6) | (((4 + lg) ^ (lr & 7)) << 3);

    gload16(Kb + c0 * 512 + lane * 8, &KV[0][c0 * 512]);
    gload16(Kb + c1 * 512 + lane * 8, &KV[0][c1 * 512]);
    gload16(Vb + c0 * 512 + lane * 8, &KV[0][4096 + c0 * 512]);
    gload16(Vb + c1 * 512 + lane * 8, &KV[0][4096 + c1 * 512]);
    __syncthreads();

    int buf = 0;
    for (int it = 0; it < NIT; ++it) {
        const int kv0 = it * 64;
        if (it + 1 < NIT) {
            const int nxt = (kv0 + 64) * 64;
            gload16(Kb + nxt + c0 * 512 + lane * 8, &KV[buf ^ 1][c0 * 512]);
            gload16(Kb + nxt + c1 * 512 + lane * 8, &KV[buf ^ 1][c1 * 512]);
            gload16(Vb + nxt + c0 * 512 + lane * 8, &KV[buf ^ 1][4096 + c0 * 512]);
            gload16(Vb + nxt + c1 * 512 + lane * 8, &KV[buf ^ 1][4096 + c1 * 512]);
        }
        const u16* Ks = &KV[buf][0];
        const u16* Vs = &KV[buf][4096];
#pragma unroll
        for (int ct = 0; ct < 4; ct++) {
            const float ma = mb[kv0 + ct * 16 + lr];
            short8 bk0 = *(const short8*)&Ks[ct * 1024 + lg * 128 + lr * 8];
            short8 bk1 = *(const short8*)&Ks[ct * 1024 + 512 + lg * 128 + lr * 8];
            floatx4 acc = {ma, ma, ma, ma};
            acc = __builtin_amdgcn_mfma_f32_16x16x32_bf16(aq0, bk0, acc, 0, 0, 0);
            acc = __builtin_amdgcn_mfma_f32_16x16x32_bf16(aq1, bk1, acc, 0, 0, 0);
#pragma unroll
            for (int rr = 0; rr < 4; rr++) {
                const float p = EXP2(acc[rr]);
                lsum[rr] += p;
                const int row = lg * 4 + rr;
                const int slot = (ct * 2 + (lr >> 3)) ^ (row & 7);
                Plds[(w << 10) | (row << 6) | (slot << 3) | (lr & 7)] = f2bf(p);
            }
        }
        // per-wave LDS P buffer: same-wave dependency, compiler inserts lgkmcnt wait
        short8 pa0 = *(const short8*)&Plds[prd0];
        short8 pa1 = *(const short8*)&Plds[prd1];
#pragma unroll
        for (int cd = 0; cd < 4; cd++) {
            short8 vb0 = *(const short8*)&Vs[cd * 1024 + lg * 128 + lr * 8];
            short8 vb1 = *(const short8*)&Vs[cd * 1024 + 512 + lg * 128 + lr * 8];
            o[cd] = __builtin_amdgcn_mfma_f32_16x16x32_bf16(pa0, vb0, o[cd], 0, 0, 0);
            o[cd] = __builtin_amdgcn_mfma_f32_16x16x32_bf16(pa1, vb1, o[cd], 0, 0, 0);
        }
        __syncthreads();   // staging complete + all reads of buf done
        buf ^= 1;
    }

#pragma unroll
    for (int rr = 0; rr < 4; rr++) {
        lsum[rr] += __shfl_xor(lsum[rr], 1);
        lsum[rr] += __shfl_xor(lsum[rr], 2);
        lsum[rr] += __shfl_xor(lsum[rr], 4);
        lsum[rr] += __shfl_xor(lsum[rr], 8);
    }

#pragma unroll
    for (int rr = 0; rr < 4; rr++) {
        const float inv = RCP(lsum[rr]);
        const int row = q0 + lg * 4 + rr;
#pragma unroll
        for (int cd = 0; cd < 4; cd++) {
            const int d = h * 64 + cd * 16 + lr;
            attn[(b * SD + row) * DD + d] = f2bf(o[cd][rr] * inv);
        }
    }
}

extern "C" void kernel_launch(void* const* d_in, const int* in_sizes, int n_in,
                              void* d_out, int out_size, void* d_ws, size_t ws_size,
                              hipStream_t stream) {
    const float* q  = (const float*)d_in[0];
    const float* k  = (const float*)d_in[1];
    const float* v  = (const float*)d_in[2];
    const int* mask = (const int*)d_in[3];
    const float* Wq = (const float*)d_in[4];
    const float* bq = (const float*)d_in[5];
    const float* Wk = (const float*)d_in[6];
    const float* bk = (const float*)d_in[7];
    const float* Wv = (const float*)d_in[8];
    const float* bv = (const float*)d_in[9];
    const float* Wo = (const float*)d_in[10];
    const float* bo = (const float*)d_in[11];
    float* out = (float*)d_out;

    u16* p = (u16*)d_ws;
    u16* qb  = p; p += MROWS * DD;
    u16* kb  = p; p += MROWS * DD;
    u16* vb  = p; p += MROWS * DD;
    u16* Wqb = p; p += DD * DD;
    u16* Wkb = p; p += DD * DD;
    u16* Wvb = p; p += DD * DD;
    u16* Wob = p; p += DD * DD;
    u16* Qh  = p; p += MROWS * DD;
    u16* Kf  = p; p += MROWS * DD;
    u16* Vf  = p; p += MROWS * DD;
    u16* attn = p; p += MROWS * DD;
    float* maskadd = (float*)p;

    cvt_all<<<dim3(512, 8), 256, 0, stream>>>((const float4*)q, (const float4*)k, (const float4*)v,
                                              (const float4*)Wq, (const float4*)Wk, (const float4*)Wv,
                                              (const float4*)Wo, mask,
                                              (u16x4*)qb, (u16x4*)kb, (u16x4*)vb,
                                              (u16x4*)Wqb, (u16x4*)Wkb, (u16x4*)Wvb, (u16x4*)Wob,
                                              maskadd);

    gemm_qkv<<<768, 256, 0, stream>>>(qb, kb, vb, Wqb, Wkb, Wvb, bq, bk, bv, Qh, Kf, Vf);

    attn_fused<<<512, 256, 0, stream>>>(Qh, Kf, Vf, maskadd, attn);

    gemm_o<<<256, 256, 0, stream>>>(attn, Wob, bo, out);
}

// Round 7
// 81.382 us; speedup vs baseline: 1.0751x; 1.0227x over previous
//
#include <hip/hip_runtime.h>

#define H 16
#define DK 64
#define SD 1024
#define DD 1024
#define BB 2
#define MROWS (BB * SD)   // 2048
#define KDIM 1024

typedef __attribute__((ext_vector_type(8))) short short8;
typedef __attribute__((ext_vector_type(4))) float floatx4;
typedef unsigned short u16;
typedef __attribute__((ext_vector_type(4))) unsigned short u16x4;

#if __has_builtin(__builtin_amdgcn_exp2f)
#define EXP2(x) __builtin_amdgcn_exp2f(x)
#else
#define EXP2(x) exp2f(x)
#endif
#if __has_builtin(__builtin_amdgcn_rcpf)
#define RCP(x) __builtin_amdgcn_rcpf(x)
#else
#define RCP(x) (1.0f / (x))
#endif

__device__ __forceinline__ u16 f2bf(float f) {
    union { float f; unsigned u; } v; v.f = f;
    unsigned u = v.u;
    return (u16)((u + 0x7FFFu + ((u >> 16) & 1u)) >> 16);
}

__device__ __forceinline__ void gload16(const void* g, void* l) {
    __builtin_amdgcn_global_load_lds((const __attribute__((address_space(1))) unsigned int*)g,
                                     (__attribute__((address_space(3))) unsigned int*)l, 16, 0, 0);
}

// ---------------- fused fp32->bf16 conversion + mask->additive ----------------
__global__ void cvt_all(const float4* __restrict__ q, const float4* __restrict__ k,
                        const float4* __restrict__ v, const float4* __restrict__ Wq,
                        const float4* __restrict__ Wk, const float4* __restrict__ Wv,
                        const float4* __restrict__ Wo, const int* __restrict__ mask,
                        u16x4* __restrict__ qb, u16x4* __restrict__ kb, u16x4* __restrict__ vb,
                        u16x4* __restrict__ Wqb, u16x4* __restrict__ Wkb, u16x4* __restrict__ Wvb,
                        u16x4* __restrict__ Wob, float* __restrict__ maskadd) {
    const int z = blockIdx.y;
    if (z == 7) {
        const int i = blockIdx.x * blockDim.x + threadIdx.x;
        if (i < BB * SD) maskadd[i] = (mask[i] != 0) ? 0.f : -1e9f;
        return;
    }
    const float4* src; u16x4* dst; int n4;
    switch (z) {
        case 0: src = q;  dst = qb;  n4 = MROWS * DD / 4; break;
        case 1: src = k;  dst = kb;  n4 = MROWS * DD / 4; break;
        case 2: src = v;  dst = vb;  n4 = MROWS * DD / 4; break;
        case 3: src = Wq; dst = Wqb; n4 = DD * DD / 4; break;
        case 4: src = Wk; dst = Wkb; n4 = DD * DD / 4; break;
        case 5: src = Wv; dst = Wvb; n4 = DD * DD / 4; break;
        default: src = Wo; dst = Wob; n4 = DD * DD / 4; break;
    }
    for (int i = blockIdx.x * blockDim.x + threadIdx.x; i < n4; i += gridDim.x * blockDim.x) {
        float4 f = src[i];
        u16x4 o;
        o.x = f2bf(f.x); o.y = f2bf(f.y); o.z = f2bf(f.z); o.w = f2bf(f.w);
        dst[i] = o;
    }
}

// ---------------- 128x64 GEMM mainloop (BK=64), DOUBLE-BUFFERED single-barrier ----------------
// r6 A/B: counted-vmcnt + raw barrier pair was +1us vs this — the __syncthreads drain is NOT
// binding at 3 blocks/CU (implicit wave overlap covers it, m114). Keep this form.
__device__ __forceinline__ void gemm_main64(const u16* __restrict__ A, const u16* __restrict__ W,
                                            u16* As, u16* Bs, floatx4 (&acc)[2][4],
                                            int row0, int col0) {
    const int tid = threadIdx.x;
    const int w = tid >> 6, lane = tid & 63, lg = lane >> 4, lr = lane & 15;
    const int lrow = lane >> 3;          // 0..7  (8 rows per 1KB wave segment)
    const int lcol = (lane & 7) * 8;     // element col within 64

    const u16* Abase = A + (row0 + lrow) * KDIM + lcol;
    const u16* Wbase = W + (col0 + lrow) * KDIM + lcol;

    // prologue: stage k0=0 into buf 0
#pragma unroll
    for (int j = 0; j < 4; j++) {
        const int seg = j * 4 + w;
        gload16(Abase + seg * 8 * KDIM, As + seg * 512);
    }
#pragma unroll
    for (int j = 0; j < 2; j++) {
        const int seg = j * 4 + w;
        gload16(Wbase + seg * 8 * KDIM, Bs + seg * 512);
    }
    __syncthreads();

    int buf = 0;
    for (int k0 = 0; k0 < KDIM; k0 += 64) {
        if (k0 + 64 < KDIM) {
            const int nb = buf ^ 1;
#pragma unroll
            for (int j = 0; j < 4; j++) {
                const int seg = j * 4 + w;
                gload16(Abase + seg * 8 * KDIM + k0 + 64, As + nb * 8192 + seg * 512);
            }
#pragma unroll
            for (int j = 0; j < 2; j++) {
                const int seg = j * 4 + w;
                gload16(Wbase + seg * 8 * KDIM + k0 + 64, Bs + nb * 4096 + seg * 512);
            }
        }
        const u16* Asb = As + buf * 8192;
        const u16* Bsb = Bs + buf * 4096;
        short8 af[2][2], bf[4][2];
#pragma unroll
        for (int kk = 0; kk < 2; kk++) {
#pragma unroll
            for (int mi = 0; mi < 2; mi++)
                af[mi][kk] = *(const short8*)&Asb[(w * 32 + mi * 16 + lr) * 64 + kk * 32 + lg * 8];
#pragma unroll
            for (int ni = 0; ni < 4; ni++)
                bf[ni][kk] = *(const short8*)&Bsb[(ni * 16 + lr) * 64 + kk * 32 + lg * 8];
        }
#pragma unroll
        for (int kk = 0; kk < 2; kk++)
#pragma unroll
            for (int mi = 0; mi < 2; mi++)
#pragma unroll
                for (int ni = 0; ni < 4; ni++)
                    acc[mi][ni] = __builtin_amdgcn_mfma_f32_16x16x32_bf16(af[mi][kk], bf[ni][kk], acc[mi][ni], 0, 0, 0);
        __syncthreads();   // drains vmcnt: next buffer staged + all reads of current done
        buf ^= 1;
    }
}

// fused Q/K/V projection, XCD-clustered 1D grid (768 blocks = 3 blocks/CU).
__global__ __launch_bounds__(256) void gemm_qkv(const u16* __restrict__ qb, const u16* __restrict__ kb,
                                                const u16* __restrict__ vb, const u16* __restrict__ Wqb,
                                                const u16* __restrict__ Wkb, const u16* __restrict__ Wvb,
                                                const float* __restrict__ bq, const float* __restrict__ bk,
                                                const float* __restrict__ bv,
                                                u16* __restrict__ Qh, u16* __restrict__ Kf, u16* __restrict__ Vf) {
    __shared__ u16 As[2 * 128 * 64];
    __shared__ u16 Bs[2 * 64 * 64];
    const int id = blockIdx.x;
    const int xcd = id & 7, j = id >> 3;
    const int z = j >> 5, r = j & 31;
    const int by = (xcd << 1) | (r >> 4), bx = r & 15;

    const u16 *A, *W; const float* bias; u16* out; float scale;
    if (z == 0)      { A = qb; W = Wqb; bias = bq; out = Qh; scale = 0.18033688011112042f; }
    else if (z == 1) { A = kb; W = Wkb; bias = bk; out = Kf; scale = 1.f; }
    else             { A = vb; W = Wvb; bias = bv; out = Vf; scale = 1.f; }

    const int row0 = by * 128, col0 = bx * 64;
    floatx4 acc[2][4] = {};
    gemm_main64(A, W, As, Bs, acc, row0, col0);

    const int tid = threadIdx.x;
    const int w = tid >> 6, lane = tid & 63, lg = lane >> 4, lr = lane & 15;
#pragma unroll
    for (int mi = 0; mi < 2; mi++)
#pragma unroll
        for (int ni = 0; ni < 4; ni++) {
            const int col = col0 + ni * 16 + lr;
            const float bv_ = bias[col];
            const int h = col >> 6, dk = col & 63;
#pragma unroll
            for (int rr = 0; rr < 4; rr++) {
                const int row = row0 + w * 32 + mi * 16 + lg * 4 + rr;
                const int b = row >> 10, s = row & 1023;
                const int bh = b * H + h;
                const float val = (acc[mi][ni][rr] + bv_) * scale;
                if (z == 0) {
                    out[(bh * SD + s) * DK + dk] = f2bf(val);
                } else if (z == 1) {
                    out[bh * 65536 + (s >> 4) * 1024 + (dk >> 5) * 512 +
                        ((dk >> 3) & 3) * 128 + (s & 15) * 8 + (dk & 7)] = f2bf(val);
                } else {
                    out[bh * 65536 + (s >> 6) * 4096 + ((dk >> 4) * 2 + ((s >> 5) & 1)) * 512 +
                        ((s >> 3) & 3) * 128 + (dk & 15) * 8 + (s & 7)] = f2bf(val);
                }
            }
        }
}

// ---------------- O-projection, XCD-clustered 1D grid (256 blocks, 128x64 tile) ----------------
__global__ __launch_bounds__(256) void gemm_o(const u16* __restrict__ A, const u16* __restrict__ W,
                                              const float* __restrict__ bias, float* __restrict__ out) {
    __shared__ u16 As[2 * 128 * 64];
    __shared__ u16 Bs[2 * 64 * 64];
    const int id = blockIdx.x;
    const int xcd = id & 7, j = id >> 3;
    const int by = (xcd << 1) | (j >> 4), bx = j & 15;
    const int row0 = by * 128, col0 = bx * 64;
    floatx4 acc[2][4] = {};
    gemm_main64(A, W, As, Bs, acc, row0, col0);

    const int tid = threadIdx.x;
    const int w = tid >> 6, lane = tid & 63, lg = lane >> 4, lr = lane & 15;
#pragma unroll
    for (int mi = 0; mi < 2; mi++)
#pragma unroll
        for (int ni = 0; ni < 4; ni++) {
            const int col = col0 + ni * 16 + lr;
            const float bv_ = bias[col];
#pragma unroll
            for (int rr = 0; rr < 4; rr++) {
                const int row = row0 + w * 32 + mi * 16 + lg * 4 + rr;
                out[row * DD + col] = acc[mi][ni][rr] + bv_;
            }
        }
}

// ---------------- fused full-KV flash attention: DIRECT L2 reads, BARRIER-FREE ----------------
// m169 pattern: per XCD the K/V working set is 4 bh x 256KB = 1MB — L2-resident. The
// fragment-linear layout makes each wave's short8 fragment read a contiguous, coalesced 1KB
// global block. So: no KV LDS, no double-buffer, no __syncthreads in the loop (Plds is
// per-wave, same-wave lgkmcnt only). Every wave is an independent stream; the compiler can
// hoist next-iter loads freely and 16 waves/CU hide the ~200cy L2 latency.
// LDS = 8KB (P only) -> occupancy VGPR-limited: __launch_bounds__(256,4) = 4 blocks/CU.
__global__ __launch_bounds__(256, 4) void attn_fused(const u16* __restrict__ Qh,
                                                     const u16* __restrict__ Kf,
                                                     const u16* __restrict__ Vf,
                                                     const float* __restrict__ maskadd,
                                                     u16* __restrict__ attn) {
    __shared__ u16 Plds[4 * 16 * 64];  // 8KB, slot-swizzled, per-wave regions
    const int id = blockIdx.x;
    const int xcd = id & 7, sblk = id >> 3;
    const int bh = (xcd << 2) | (sblk >> 4);
    const int qx = sblk & 15;
    const int b = bh >> 4, h = bh & 15;
    const int tid = threadIdx.x;
    const int w = tid >> 6, lane = tid & 63;
    const int lg = lane >> 4, lr = lane & 15;
    const int q0 = qx * 64 + w * 16;

    const u16* Qb = Qh + bh * SD * DK;
    const u16* Kb = Kf + bh * 65536;
    const u16* Vb = Vf + bh * 65536;
    const float* mb = maskadd + b * SD;

    short8 aq0 = *(const short8*)&Qb[(q0 + lr) * DK + lg * 8];
    short8 aq1 = *(const short8*)&Qb[(q0 + lr) * DK + 32 + lg * 8];

    floatx4 o[4] = {};
    float lsum[4] = {0.f, 0.f, 0.f, 0.f};

    const int NIT = SD / 64;           // 16

    // P read addresses (swizzled): row = lr, slots lg and 4+lg
    const int prd0 = (w << 10) | (lr << 6) | ((lg ^ (lr & 7)) << 3);
    const int prd1 = (w << 10) | (lr << 6) | (((4 + lg) ^ (lr & 7)) << 3);

    for (int it = 0; it < NIT; ++it) {
        const int kv0 = it * 64;
        const u16* Ks = Kb + kv0 * 64;   // 8KB fragment-linear K tile (64 rows)
        const u16* Vs = Vb + kv0 * 64;   // 8KB fragment-linear V tile
#pragma unroll
        for (int ct = 0; ct < 4; ct++) {
            const float ma = mb[kv0 + ct * 16 + lr];
            short8 bk0 = *(const short8*)&Ks[ct * 1024 + lg * 128 + lr * 8];
            short8 bk1 = *(const short8*)&Ks[ct * 1024 + 512 + lg * 128 + lr * 8];
            floatx4 acc = {ma, ma, ma, ma};
            acc = __builtin_amdgcn_mfma_f32_16x16x32_bf16(aq0, bk0, acc, 0, 0, 0);
            acc = __builtin_amdgcn_mfma_f32_16x16x32_bf16(aq1, bk1, acc, 0, 0, 0);
#pragma unroll
            for (int rr = 0; rr < 4; rr++) {
                const float p = EXP2(acc[rr]);
                lsum[rr] += p;
                const int row = lg * 4 + rr;
                const int slot = (ct * 2 + (lr >> 3)) ^ (row & 7);
                Plds[(w << 10) | (row << 6) | (slot << 3) | (lr & 7)] = f2bf(p);
            }
        }
        // per-wave LDS P buffer: same-wave dependency, compiler inserts lgkmcnt wait
        short8 pa0 = *(const short8*)&Plds[prd0];
        short8 pa1 = *(const short8*)&Plds[prd1];
#pragma unroll
        for (int cd = 0; cd < 4; cd++) {
            short8 vb0 = *(const short8*)&Vs[cd * 1024 + lg * 128 + lr * 8];
            short8 vb1 = *(const short8*)&Vs[cd * 1024 + 512 + lg * 128 + lr * 8];
            o[cd] = __builtin_amdgcn_mfma_f32_16x16x32_bf16(pa0, vb0, o[cd], 0, 0, 0);
            o[cd] = __builtin_amdgcn_mfma_f32_16x16x32_bf16(pa1, vb1, o[cd], 0, 0, 0);
        }
        // no barrier: Plds region is private to this wave; K/V tiles are read-only
    }

#pragma unroll
    for (int rr = 0; rr < 4; rr++) {
        lsum[rr] += __shfl_xor(lsum[rr], 1);
        lsum[rr] += __shfl_xor(lsum[rr], 2);
        lsum[rr] += __shfl_xor(lsum[rr], 4);
        lsum[rr] += __shfl_xor(lsum[rr], 8);
    }

#pragma unroll
    for (int rr = 0; rr < 4; rr++) {
        const float inv = RCP(lsum[rr]);
        const int row = q0 + lg * 4 + rr;
#pragma unroll
        for (int cd = 0; cd < 4; cd++) {
            const int d = h * 64 + cd * 16 + lr;
            attn[(b * SD + row) * DD + d] = f2bf(o[cd][rr] * inv);
        }
    }
}

extern "C" void kernel_launch(void* const* d_in, const int* in_sizes, int n_in,
                              void* d_out, int out_size, void* d_ws, size_t ws_size,
                              hipStream_t stream) {
    const float* q  = (const float*)d_in[0];
    const float* k  = (const float*)d_in[1];
    const float* v  = (const float*)d_in[2];
    const int* mask = (const int*)d_in[3];
    const float* Wq = (const float*)d_in[4];
    const float* bq = (const float*)d_in[5];
    const float* Wk = (const float*)d_in[6];
    const float* bk = (const float*)d_in[7];
    const float* Wv = (const float*)d_in[8];
    const float* bv = (const float*)d_in[9];
    const float* Wo = (const float*)d_in[10];
    const float* bo = (const float*)d_in[11];
    float* out = (float*)d_out;

    u16* p = (u16*)d_ws;
    u16* qb  = p; p += MROWS * DD;
    u16* kb  = p; p += MROWS * DD;
    u16* vb  = p; p += MROWS * DD;
    u16* Wqb = p; p += DD * DD;
    u16* Wkb = p; p += DD * DD;
    u16* Wvb = p; p += DD * DD;
    u16* Wob = p; p += DD * DD;
    u16* Qh  = p; p += MROWS * DD;
    u16* Kf  = p; p += MROWS * DD;
    u16* Vf  = p; p += MROWS * DD;
    u16* attn = p; p += MROWS * DD;
    float* maskadd = (float*)p;

    cvt_all<<<dim3(512, 8), 256, 0, stream>>>((const float4*)q, (const float4*)k, (const float4*)v,
                                              (const float4*)Wq, (const float4*)Wk, (const float4*)Wv,
                                              (const float4*)Wo, mask,
                                              (u16x4*)qb, (u16x4*)kb, (u16x4*)vb,
                                              (u16x4*)Wqb, (u16x4*)Wkb, (u16x4*)Wvb, (u16x4*)Wob,
                                              maskadd);

    gemm_qkv<<<768, 256, 0, stream>>>(qb, kb, vb, Wqb, Wkb, Wvb, bq, bk, bv, Qh, Kf, Vf);

    attn_fused<<<512, 256, 0, stream>>>(Qh, Kf, Vf, maskadd, attn);

    gemm_o<<<256, 256, 0, stream>>>(attn, Wob, bo, out);
}